// Round 1
// baseline (72.161 us; speedup 1.0000x reference)
//
#include <hip/hip_runtime.h>
#include <cstdint>
#include <cstddef>

typedef unsigned short u16;
typedef __attribute__((ext_vector_type(8))) short short8;
typedef __attribute__((ext_vector_type(4))) float f32x4;

__device__ __forceinline__ u16 f2bf(float f){
  union { float f; unsigned u; } c; c.f = f;
  unsigned u = c.u;
  u += 0x7fffu + ((u >> 16) & 1u);   // RNE
  return (u16)(u >> 16);
}
__device__ __forceinline__ float bf2f(u16 h){
  union { unsigned u; float f; } c; c.u = ((unsigned)h) << 16; return c.f;
}

// ---------------------------------------------------------------------------
// Kernel 1: transpose x [b][128ci][4096pos] fp32 -> xT [b][4096pos][128ci] bf16
//           + per-(b,chunk,ci) partial sums for SE global-avg-pool
// grid (32 chunks, 16 b), 256 threads. LDS tile 128pos x 130ci (pad -> 2-way free)
// ---------------------------------------------------------------------------
__global__ void xpose_pool(const float* __restrict__ x, u16* __restrict__ xT,
                           float* __restrict__ part)
{
  const int b = blockIdx.y, chunk = blockIdx.x;
  const int pos0 = chunk << 7;
  const int tid = threadIdx.x;
  __shared__ u16 tile[128][130];
  __shared__ float pp[256];
  const float* xb = x + ((size_t)b << 19);   // b*128*4096
  const int p = tid & 127, half = tid >> 7;

  for (int it = 0; it < 64; ++it){
    int ci = (it << 1) + half;
    tile[p][ci] = f2bf(xb[((size_t)ci << 12) + pos0 + p]);  // coalesced along p
  }
  __syncthreads();
  {
    const int ci = tid & 127, prt = tid >> 7;
    float s = 0.f;
    #pragma unroll 8
    for (int q = 0; q < 64; ++q) s += bf2f(tile[(prt << 6) + q][ci]);
    pp[tid] = s;
  }
  __syncthreads();
  if (tid < 128) part[((b << 5) + chunk) * 128 + tid] = pp[tid] + pp[tid + 128];

  u16* xo = xT + (((size_t)(b << 12) + pos0) << 7);
  for (int it = 0; it < 64; ++it){
    int pr = (it << 1) + half;
    xo[((size_t)pr << 7) + p] = tile[pr][p];                // coalesced along ci
  }
}

// ---------------------------------------------------------------------------
// Kernel 2: finish pooling, SE MLP, softmax(logits/30) -> attn[16][4]
// grid 16, 128 threads
// ---------------------------------------------------------------------------
__global__ void attn_fc(const float* __restrict__ part, const float* __restrict__ w1,
                        const float* __restrict__ w2, const float* __restrict__ b2,
                        float* __restrict__ attn)
{
  const int b = blockIdx.x, t = threadIdx.x;
  __shared__ float sp[128];
  __shared__ float sh[33];
  __shared__ float sl[4];
  const float* pb = part + (b << 12);        // b*32*128
  float s = 0.f;
  for (int c = 0; c < 32; ++c) s += pb[(c << 7) + t];
  sp[t] = s * (1.f / 4096.f);
  __syncthreads();
  if (t < 33){
    float h = 0.f;
    for (int ci = 0; ci < 128; ++ci) h += sp[ci] * w1[t * 128 + ci];
    sh[t] = fmaxf(h, 0.f);
  }
  __syncthreads();
  if (t < 4){
    float l = b2[t];
    for (int j = 0; j < 33; ++j) l += sh[j] * w2[t * 33 + j];
    sl[t] = l * (1.f / 30.f);
  }
  __syncthreads();
  if (t == 0){
    float m = fmaxf(fmaxf(sl[0], sl[1]), fmaxf(sl[2], sl[3]));
    float e0 = __expf(sl[0] - m), e1 = __expf(sl[1] - m);
    float e2 = __expf(sl[2] - m), e3 = __expf(sl[3] - m);
    float inv = 1.f / (e0 + e1 + e2 + e3);
    attn[(b << 2) + 0] = e0 * inv; attn[(b << 2) + 1] = e1 * inv;
    attn[(b << 2) + 2] = e2 * inv; attn[(b << 2) + 3] = e3 * inv;
  }
}

// ---------------------------------------------------------------------------
// Kernel 3: wcomb[b][tap][co][ci] = sum_k attn[b][k]*W[k*128+co][ci][tap] (bf16)
//           bcomb[b][co]          = sum_k attn[b][k]*bias[k*128+co]
// grid 128 (one co each), 256 threads. W slice for this co staged in LDS.
// ---------------------------------------------------------------------------
__global__ void combine(const float* __restrict__ W, const float* __restrict__ bias,
                        const float* __restrict__ attn, u16* __restrict__ wcomb,
                        float* __restrict__ bcomb)
{
  const int co = blockIdx.x, tid = threadIdx.x;
  __shared__ float wk[4][1152];
  __shared__ float sat[64];
  if (tid < 64) sat[tid] = attn[tid];
  for (int idx = tid; idx < 4608; idx += 256){
    int k = idx / 1152, j = idx - k * 1152;
    wk[k][j] = W[(size_t)(k * 128 + co) * 1152 + j];
  }
  __syncthreads();
  if (tid < 16){
    float s = 0.f;
    #pragma unroll
    for (int k = 0; k < 4; ++k) s += sat[(tid << 2) + k] * bias[(k << 7) + co];
    bcomb[(tid << 7) + co] = s;
  }
  for (int odx = tid; odx < 18432; odx += 256){
    int bq = odx / 1152, r = odx - bq * 1152;
    int tap = r >> 7, ci = r & 127;
    int j = ci * 9 + tap;  // LDS stride-9 reads: 9 coprime 32 -> conflict-free
    float s = sat[bq << 2]       * wk[0][j] + sat[(bq << 2) + 1] * wk[1][j]
            + sat[(bq << 2) + 2] * wk[2][j] + sat[(bq << 2) + 3] * wk[3][j];
    wcomb[(size_t)(((bq * 9 + tap) << 7) + co) * 128 + ci] = f2bf(s);
  }
}

// ---------------------------------------------------------------------------
// Kernel 4: dynamic conv as 9-tap implicit GEMM, bf16 MFMA 16x16x32.
// grid (16 h-tiles, 16 b), 512 threads (8 waves: 4 rows x 2 co-halves).
// LDS: s_wa [128co][16 koct]x16B XOR-swizzled (32KB),
//      s_xt [6 rows][16 ci-oct][66 cols][8ci] bf16 (101.4KB). Total 134144B.
// Per wave: 4 co-frags x 4 pos-frags accumulators (64 f32 regs).
// ---------------------------------------------------------------------------
__global__ __launch_bounds__(512, 2) void conv_mfma(
    const u16* __restrict__ xT, const u16* __restrict__ wcomb,
    const float* __restrict__ bcomb, float* __restrict__ out)
{
  extern __shared__ char smem[];
  u16* s_wa = (u16*)smem;              // 2048 granules * 16B
  u16* s_xt = (u16*)(smem + 32768);    // 6336 granules * 16B

  const int tid = threadIdx.x;
  const int lane = tid & 63, wid = tid >> 6;
  const int wr = wid & 3, wc = wid >> 1 >> 1;   // wr: row 0..3, wc: co half 0..1
  const int l15 = lane & 15, hi = lane >> 4;
  const int b = blockIdx.y, h0 = blockIdx.x << 2;

  // ---- stage x tile: rows h0-1..h0+4 (6), cols -1..64 (66), all 128 ci ----
  {
    const u16* xtb = xT + ((size_t)b << 19);    // b*4096*128
    for (int g = tid; g < 6336; g += 512){
      int oct = g & 15;
      int t = g >> 4;
      int col = t % 66;
      int row = t / 66;
      int h = h0 - 1 + row, w = col - 1;
      uint4 v = make_uint4(0u, 0u, 0u, 0u);
      if ((unsigned)h < 64u && (unsigned)w < 64u)
        v = *(const uint4*)(xtb + ((size_t)(((h << 6) + w) << 7) + (oct << 3)));
      *(uint4*)(s_xt + ((((row << 4) + oct) * 66 + col) << 3)) = v;
    }
  }

  f32x4 acc[4][4] = {};

  const u16* wb = wcomb + (size_t)b * (9 * 128 * 128);
  for (int tap = 0; tap < 9; ++tap){
    __syncthreads();   // protect s_wa from prior reads; tap0: no-op cost
    {
      const u16* wt = wb + tap * 16384;
      #pragma unroll
      for (int it = 0; it < 4; ++it){
        int g = tid + it * 512;
        int co = g >> 4, koct = g & 15;
        uint4 v = *(const uint4*)(wt + ((size_t)g << 3));
        *(uint4*)(s_wa + (((co << 4) + (koct ^ (co & 7))) << 3)) = v;
      }
    }
    __syncthreads();   // s_wa (tap0: also s_xt) ready

    const int dh = tap / 3, dw = tap - dh * 3;
    const int row = wr + dh;
    const int cbase = l15 + dw;
    #pragma unroll
    for (int kc = 0; kc < 4; ++kc){
      const int koct = (kc << 2) + hi;
      short8 af[4], bfr[4];
      #pragma unroll
      for (int cf = 0; cf < 4; ++cf){
        int co = (wc << 6) + (cf << 4) + l15;   // A row = lane&15
        af[cf] = *(const short8*)(s_wa + (((co << 4) + (koct ^ (l15 & 7))) << 3));
      }
      #pragma unroll
      for (int pf = 0; pf < 4; ++pf){
        bfr[pf] = *(const short8*)(s_xt + ((((row << 4) + koct) * 66 + (pf << 4) + cbase) << 3));
      }
      #pragma unroll
      for (int cf = 0; cf < 4; ++cf)
        #pragma unroll
        for (int pf = 0; pf < 4; ++pf)
          acc[cf][pf] = __builtin_amdgcn_mfma_f32_16x16x32_bf16(af[cf], bfr[pf], acc[cf][pf], 0, 0, 0);
    }
  }

  // ---- epilogue: C/D layout col=lane&15 (pos), row=(lane>>4)*4+reg (co) ----
  const int h = h0 + wr;
  float* ob = out + ((size_t)b << 19);          // b*128*4096
  #pragma unroll
  for (int cf = 0; cf < 4; ++cf){
    const int co0 = (wc << 6) + (cf << 4) + (hi << 2);
    float bc[4];
    #pragma unroll
    for (int r = 0; r < 4; ++r) bc[r] = bcomb[(b << 7) + co0 + r];
    #pragma unroll
    for (int pf = 0; pf < 4; ++pf){
      #pragma unroll
      for (int r = 0; r < 4; ++r){
        ob[(size_t)(co0 + r) * 4096 + (h << 6) + (pf << 4) + l15] = acc[cf][pf][r] + bc[r];
      }
    }
  }
}

// ---------------------------------------------------------------------------
extern "C" void kernel_launch(void* const* d_in, const int* in_sizes, int n_in,
                              void* d_out, int out_size, void* d_ws, size_t ws_size,
                              hipStream_t stream)
{
  const float* x    = (const float*)d_in[0];
  const float* W    = (const float*)d_in[1];
  const float* bias = (const float*)d_in[2];
  const float* w1   = (const float*)d_in[3];
  const float* w2   = (const float*)d_in[4];
  const float* b2   = (const float*)d_in[5];
  float* out = (float*)d_out;

  char* ws = (char*)d_ws;
  float* part  = (float*)(ws);               // 16*32*128*4   = 262144 B
  float* attn  = (float*)(ws + 262144);      // 16*4*4        = 256 B
  float* bcomb = (float*)(ws + 262400);      // 16*128*4      = 8192 B
  u16*   xT    = (u16*)  (ws + 270592);      // 16*4096*128*2 = 16777216 B
  u16*   wcomb = (u16*)  (ws + 17047808);    // 16*9*128*128*2= 4718592 B  (end ~21.8MB)

  xpose_pool<<<dim3(32, 16), 256, 0, stream>>>(x, xT, part);
  attn_fc<<<16, 128, 0, stream>>>(part, w1, w2, b2, attn);
  combine<<<128, 256, 0, stream>>>(W, bias, attn, wcomb, bcomb);

  (void)hipFuncSetAttribute(reinterpret_cast<const void*>(conv_mfma),
                            hipFuncAttributeMaxDynamicSharedMemorySize, 134144);
  conv_mfma<<<dim3(16, 16), 512, 134144, stream>>>(xT, wcomb, bcomb, out);
}

// Round 2
// 67.475 us; speedup vs baseline: 1.0695x; 1.0695x over previous
//
#include <hip/hip_runtime.h>
#include <cstdint>
#include <cstddef>

typedef unsigned short u16;
typedef __attribute__((ext_vector_type(8))) short short8;
typedef __attribute__((ext_vector_type(4))) float f32x4;

__device__ __forceinline__ u16 f2bf(float f){
  union { float f; unsigned u; } c; c.f = f;
  unsigned u = c.u;
  u += 0x7fffu + ((u >> 16) & 1u);   // RNE
  return (u16)(u >> 16);
}
__device__ __forceinline__ unsigned pk2(float a, float b){
  // pack two fp32 -> two bf16 (round-half-away; |err| <= 0.5 ulp, fine vs 7e-2 budget)
  union { float f; unsigned u; } ca, cb; ca.f = a; cb.f = b;
  return ((ca.u + 0x8000u) >> 16) | ((cb.u + 0x8000u) & 0xFFFF0000u);
}

// ---------------------------------------------------------------------------
// Kernel 1: transpose x [b][128ci][4096pos] fp32 -> xT [b][4096pos][128ci] bf16
//           + per-(b,chunk,ci) partial sums for SE global-avg-pool.
// grid (32 chunks, 16 b), 256 threads. Tile 128pos x 128ci, granule-swizzled:
// granule g (8 ci = 16B) stored at position g ^ ((row>>2)&7).
// Writes: b128, each bank-quad gets 8 lanes/waveop -> conflict-free.
// Reads:  b128, 2-way (free). Global: float4 in, uint4 out, all coalesced.
// ---------------------------------------------------------------------------
__global__ __launch_bounds__(256) void xpose_pool(
    const float* __restrict__ x, u16* __restrict__ xT, float* __restrict__ part)
{
  const int b = blockIdx.y, chunk = blockIdx.x;
  const int pos0 = chunk << 7;
  const int tid = threadIdx.x;
  __shared__ u16 tile[16384];        // 32 KB, swizzled [row][g'][8ci]
  __shared__ float psum[128 * 33];   // 16.9 KB, pad 33 -> conflict-free
  const float* xb = x + ((size_t)b << 19) + pos0;
  const int p4 = (tid & 31) << 2;
  const int swz = (tid & 31) & 7;    // (row>>2)&7 is constant = tid&31 (&7)

  #pragma unroll
  for (int i = 0; i < 2; ++i){
    const int gci = (tid >> 5) + (i << 3);   // granule 0..15
    const int ci8 = gci << 3;
    float4 L[8];
    #pragma unroll
    for (int j = 0; j < 8; ++j)
      L[j] = *(const float4*)(xb + ((size_t)(ci8 + j) << 12) + p4);
    #pragma unroll
    for (int j = 0; j < 8; ++j)
      psum[(ci8 + j) * 33 + (tid & 31)] = L[j].x + L[j].y + L[j].z + L[j].w;
    const int gs = gci ^ swz;
    const float* e = (const float*)L;
    #pragma unroll
    for (int p = 0; p < 4; ++p){
      const int row = p4 + p;
      uint4 V;
      V.x = pk2(e[0 * 4 + p], e[1 * 4 + p]);
      V.y = pk2(e[2 * 4 + p], e[3 * 4 + p]);
      V.z = pk2(e[4 * 4 + p], e[5 * 4 + p]);
      V.w = pk2(e[6 * 4 + p], e[7 * 4 + p]);
      *(uint4*)(tile + (row << 7) + (gs << 3)) = V;
    }
  }
  __syncthreads();

  if (tid < 128){
    float s = 0.f;
    #pragma unroll 8
    for (int j = 0; j < 32; ++j) s += psum[tid * 33 + j];
    part[((b << 5) + chunk) * 128 + tid] = s;
  }

  u16* xo = xT + ((((size_t)b << 12) + pos0) << 7);
  const int g = tid & 15, rb = (tid >> 4) << 3;
  #pragma unroll
  for (int r = 0; r < 8; ++r){
    const int row = rb + r;
    const int gs = g ^ ((row >> 2) & 7);
    uint4 v = *(const uint4*)(tile + (row << 7) + (gs << 3));
    *(uint4*)(xo + ((size_t)row << 7) + (g << 3)) = v;
  }
}

// ---------------------------------------------------------------------------
// Kernel 2: finish pooling, SE MLP, softmax(logits/30) -> attn[16][4]
// ---------------------------------------------------------------------------
__global__ void attn_fc(const float* __restrict__ part, const float* __restrict__ w1,
                        const float* __restrict__ w2, const float* __restrict__ b2,
                        float* __restrict__ attn)
{
  const int b = blockIdx.x, t = threadIdx.x;
  __shared__ float sp[128];
  __shared__ float sh[33];
  __shared__ float sl[4];
  const float* pb = part + (b << 12);
  float s = 0.f;
  for (int c = 0; c < 32; ++c) s += pb[(c << 7) + t];
  sp[t] = s * (1.f / 4096.f);
  __syncthreads();
  if (t < 33){
    float h = 0.f;
    for (int ci = 0; ci < 128; ++ci) h += sp[ci] * w1[t * 128 + ci];
    sh[t] = fmaxf(h, 0.f);
  }
  __syncthreads();
  if (t < 4){
    float l = b2[t];
    for (int j = 0; j < 33; ++j) l += sh[j] * w2[t * 33 + j];
    sl[t] = l * (1.f / 30.f);
  }
  __syncthreads();
  if (t == 0){
    float m = fmaxf(fmaxf(sl[0], sl[1]), fmaxf(sl[2], sl[3]));
    float e0 = __expf(sl[0] - m), e1 = __expf(sl[1] - m);
    float e2 = __expf(sl[2] - m), e3 = __expf(sl[3] - m);
    float inv = 1.f / (e0 + e1 + e2 + e3);
    attn[(b << 2) + 0] = e0 * inv; attn[(b << 2) + 1] = e1 * inv;
    attn[(b << 2) + 2] = e2 * inv; attn[(b << 2) + 3] = e3 * inv;
  }
}

// ---------------------------------------------------------------------------
// Kernel 3: wcomb[b][tap][co][ci] = sum_k attn[b][k]*W[k*128+co][ci][tap] (bf16)
//           bcomb[b][co]          = sum_k attn[b][k]*bias[k*128+co]
// ---------------------------------------------------------------------------
__global__ void combine(const float* __restrict__ W, const float* __restrict__ bias,
                        const float* __restrict__ attn, u16* __restrict__ wcomb,
                        float* __restrict__ bcomb)
{
  const int co = blockIdx.x, tid = threadIdx.x;
  __shared__ float wk[4][1152];
  __shared__ float sat[64];
  if (tid < 64) sat[tid] = attn[tid];
  for (int idx = tid; idx < 4608; idx += 256){
    int k = idx / 1152, j = idx - k * 1152;
    wk[k][j] = W[(size_t)(k * 128 + co) * 1152 + j];
  }
  __syncthreads();
  if (tid < 16){
    float s = 0.f;
    #pragma unroll
    for (int k = 0; k < 4; ++k) s += sat[(tid << 2) + k] * bias[(k << 7) + co];
    bcomb[(tid << 7) + co] = s;
  }
  for (int odx = tid; odx < 18432; odx += 256){
    int bq = odx / 1152, r = odx - bq * 1152;
    int tap = r >> 7, ci = r & 127;
    int j = ci * 9 + tap;
    float s = sat[bq << 2]       * wk[0][j] + sat[(bq << 2) + 1] * wk[1][j]
            + sat[(bq << 2) + 2] * wk[2][j] + sat[(bq << 2) + 3] * wk[3][j];
    wcomb[(size_t)(((bq * 9 + tap) << 7) + co) * 128 + ci] = f2bf(s);
  }
}

// ---------------------------------------------------------------------------
// Kernel 4: dynamic conv as 9-tap implicit GEMM, bf16 MFMA 16x16x32.
// 1D grid 256, XCD-clustered decode (both tile-groups of a batch share an XCD
// so the 16 re-reads of wcomb[b] (295KB) stay L2-local).
// 512 threads (8 waves: 4 rows x 2 co-halves), 134144 B dynamic LDS.
// Weight staging double-hopped via regs: tap t+1 global loads issued under
// tap t's MFMA phase (T14 async-split).
// ---------------------------------------------------------------------------
__global__ __launch_bounds__(512, 2) void conv_mfma(
    const u16* __restrict__ xT, const u16* __restrict__ wcomb,
    const float* __restrict__ bcomb, float* __restrict__ out)
{
  extern __shared__ char smem[];
  u16* s_wa = (u16*)smem;              // [128co][16 koct]x16B, XOR-swizzled (32KB)
  u16* s_xt = (u16*)(smem + 32768);    // [6 rows][16 oct][66 cols][8ci] (101.4KB)

  const int tid = threadIdx.x;
  const int lane = tid & 63, wid = tid >> 6;
  const int wr = wid & 3, wc = wid >> 2;
  const int l15 = lane & 15, hi = lane >> 4;

  const int bid = blockIdx.x;
  const int xcd = bid & 7, idx = bid >> 3;
  const int b = (xcd << 1) | (idx >> 4);   // 2 batches per XCD
  const int h0 = (idx & 15) << 2;

  // ---- stage x tile: rows h0-1..h0+4 (6), cols -1..64 (66), all 128 ci ----
  {
    const u16* xtb = xT + ((size_t)b << 19);
    for (int g = tid; g < 6336; g += 512){
      int oct = g & 15;
      int t = g >> 4;
      int col = t % 66;
      int row = t / 66;
      int h = h0 - 1 + row, w = col - 1;
      uint4 v = make_uint4(0u, 0u, 0u, 0u);
      if ((unsigned)h < 64u && (unsigned)w < 64u)
        v = *(const uint4*)(xtb + ((size_t)(((h << 6) + w) << 7) + (oct << 3)));
      *(uint4*)(s_xt + ((((row << 4) + oct) * 66 + col) << 3)) = v;
    }
  }

  f32x4 acc[4][4] = {};

  const u16* wb = wcomb + (size_t)b * (9 * 128 * 128);
  uint4 wreg[4];
  #pragma unroll
  for (int it = 0; it < 4; ++it)
    wreg[it] = *(const uint4*)(wb + ((size_t)(tid + it * 512) << 3));

  for (int tap = 0; tap < 9; ++tap){
    __syncthreads();   // prior compute done reading s_wa (tap0: also orders s_xt)
    #pragma unroll
    for (int it = 0; it < 4; ++it){
      int g = tid + it * 512;
      int co = g >> 4, koct = g & 15;
      *(uint4*)(s_wa + (((co << 4) + (koct ^ (co & 7))) << 3)) = wreg[it];
    }
    if (tap < 8){
      const u16* wt = wb + (tap + 1) * 16384;
      #pragma unroll
      for (int it = 0; it < 4; ++it)
        wreg[it] = *(const uint4*)(wt + ((size_t)(tid + it * 512) << 3));
    }
    __syncthreads();   // s_wa ready

    const int dh = tap / 3, dw = tap - dh * 3;
    const int row = wr + dh;
    const int cbase = l15 + dw;
    #pragma unroll
    for (int kc = 0; kc < 4; ++kc){
      const int koct = (kc << 2) + hi;
      short8 af[4], bfr[4];
      #pragma unroll
      for (int cf = 0; cf < 4; ++cf){
        int co = (wc << 6) + (cf << 4) + l15;
        af[cf] = *(const short8*)(s_wa + (((co << 4) + (koct ^ (l15 & 7))) << 3));
      }
      #pragma unroll
      for (int pf = 0; pf < 4; ++pf){
        bfr[pf] = *(const short8*)(s_xt + ((((row << 4) + koct) * 66 + (pf << 4) + cbase) << 3));
      }
      #pragma unroll
      for (int cf = 0; cf < 4; ++cf)
        #pragma unroll
        for (int pf = 0; pf < 4; ++pf)
          acc[cf][pf] = __builtin_amdgcn_mfma_f32_16x16x32_bf16(af[cf], bfr[pf], acc[cf][pf], 0, 0, 0);
    }
  }

  // ---- epilogue: C/D layout col=lane&15 (pos), row=(lane>>4)*4+reg (co) ----
  const int h = h0 + wr;
  float* ob = out + ((size_t)b << 19);
  #pragma unroll
  for (int cf = 0; cf < 4; ++cf){
    const int co0 = (wc << 6) + (cf << 4) + (hi << 2);
    float bc[4];
    #pragma unroll
    for (int r = 0; r < 4; ++r) bc[r] = bcomb[(b << 7) + co0 + r];
    #pragma unroll
    for (int pf = 0; pf < 4; ++pf){
      #pragma unroll
      for (int r = 0; r < 4; ++r){
        ob[(size_t)(co0 + r) * 4096 + (h << 6) + (pf << 4) + l15] = acc[cf][pf][r] + bc[r];
      }
    }
  }
}

// ---------------------------------------------------------------------------
extern "C" void kernel_launch(void* const* d_in, const int* in_sizes, int n_in,
                              void* d_out, int out_size, void* d_ws, size_t ws_size,
                              hipStream_t stream)
{
  const float* x    = (const float*)d_in[0];
  const float* W    = (const float*)d_in[1];
  const float* bias = (const float*)d_in[2];
  const float* w1   = (const float*)d_in[3];
  const float* w2   = (const float*)d_in[4];
  const float* b2   = (const float*)d_in[5];
  float* out = (float*)d_out;

  char* ws = (char*)d_ws;
  float* part  = (float*)(ws);               // 16*32*128*4   = 262144 B
  float* attn  = (float*)(ws + 262144);      // 256 B
  float* bcomb = (float*)(ws + 262400);      // 8192 B
  u16*   xT    = (u16*)  (ws + 270592);      // 16 MB
  u16*   wcomb = (u16*)  (ws + 17047808);    // 4.7 MB

  xpose_pool<<<dim3(32, 16), 256, 0, stream>>>(x, xT, part);
  attn_fc<<<16, 128, 0, stream>>>(part, w1, w2, b2, attn);
  combine<<<128, 256, 0, stream>>>(W, bias, attn, wcomb, bcomb);

  (void)hipFuncSetAttribute(reinterpret_cast<const void*>(conv_mfma),
                            hipFuncAttributeMaxDynamicSharedMemorySize, 134144);
  conv_mfma<<<256, 512, 134144, stream>>>(xT, wcomb, bcomb, out);
}